// Round 1
// baseline (470.126 us; speedup 1.0000x reference)
//
#include <hip/hip_runtime.h>
#include <hip/hip_bf16.h>
#include <stdint.h>

#define B_      8
#define GRID_   24
#define C_      768
#define NPATCH  (B_*GRID_*GRID_)   // 4608
#define PRE     1024
#define TGT     1024
#define NMEM    20000
#define NMEM_PAD 20224             // 79 * 256
#define IMG_    384
#define SEQ     577                // GRID*GRID + 1

typedef __bf16 bf16_t;
typedef bf16_t bf16x8 __attribute__((ext_vector_type(8)));
typedef bf16_t bf16x4 __attribute__((ext_vector_type(4)));
typedef float  floatx4 __attribute__((ext_vector_type(4)));

// ---------------------------------------------------------------------------
// Kernel A: per-patch pooled embedding, register-direct.
// ---------------------------------------------------------------------------
__global__ __launch_bounds__(256) void emb_kernel(
    const float* __restrict__ f6, const float* __restrict__ f8,
    const float* __restrict__ f10,
    bf16_t* __restrict__ emb, float* __restrict__ enorm)
{
    __shared__ float pooled[3*PRE];   // 12 KB
    __shared__ float red[4];

    const int n   = blockIdx.x;
    const int b   = n / (GRID_*GRID_);
    const int yx  = n - b*(GRID_*GRID_);
    const int y   = yx / GRID_;
    const int x   = yx - y*GRID_;
    const int t   = threadIdx.x;

    const float* fl[3] = {f6, f8, f10};

#pragma unroll
    for (int l = 0; l < 3; ++l) {
        const float* f = fl[l];
        float A0 = 0.f, B0 = 0.f, C1 = 0.f, D1 = 0.f, E2 = 0.f, F2 = 0.f;
#pragma unroll
        for (int k = 0; k < 9; ++k) {
            const int kh = k / 3, kw = k - kh*3;
            const int ny = y + kh - 1, nx = x + kw - 1;
            const bool v = (ny >= 0 && ny < GRID_ && nx >= 0 && nx < GRID_);
            const int off = v ? (b*SEQ + 1 + ny*GRID_ + nx) : (b*SEQ);
            const float* p = f + (size_t)off*C_ + 3*t;
            float a = p[0], bq = p[1], c = p[2];
            if (!v) { a = 0.f; bq = 0.f; c = 0.f; }
            if (k <= 6) A0 += a;
            if (k >= 6) B0 += a;
            if (k <= 4) C1 += bq;
            if (k >= 4) D1 += bq;
            if (k <= 2) E2 += c;
            if (k >= 2) F2 += c;
        }
        float4 pv;
        pv.x = A0 * (1.f/7.f);
        pv.y = (B0 + C1) * (1.f/8.f);
        pv.z = (D1 + E2) * (1.f/8.f);
        pv.w = F2 * (1.f/7.f);
        *(float4*)(pooled + l*PRE + 4*t) = pv;
    }
    __syncthreads();

    float psq = 0.f;
    bf16x4 ev;
#pragma unroll
    for (int r = 0; r < 4; ++r) {
        const int j = 4*t + r;
        float vv = (pooled[3*j] + pooled[3*j+1] + pooled[3*j+2]) * (1.f/3.f);
        ev[r] = (bf16_t)vv;
        psq += vv*vv;
    }
    *(bf16x4*)(emb + (size_t)n*TGT + 4*t) = ev;

    for (int off = 32; off > 0; off >>= 1) psq += __shfl_down(psq, off, 64);
    if ((t & 63) == 0) red[t >> 6] = psq;
    __syncthreads();
    if (t == 0) enorm[n] = (red[0] + red[1]) + (red[2] + red[3]);
}

// ---------------------------------------------------------------------------
// Kernel M: memory_bank fp32 -> bf16 (padded rows zeroed) + ||m||^2, float4.
// ---------------------------------------------------------------------------
__global__ __launch_bounds__(256) void mprep_kernel(
    const float* __restrict__ mb, bf16_t* __restrict__ mbf,
    float* __restrict__ mnorm)
{
    const int r = blockIdx.x;
    const int t = threadIdx.x;
    __shared__ float red[4];
    float psq = 0.f;
    if (r < NMEM) {
        float4 v = ((const float4*)(mb + (size_t)r*TGT))[t];
        bf16x4 o;
        o[0] = (bf16_t)v.x; o[1] = (bf16_t)v.y;
        o[2] = (bf16_t)v.z; o[3] = (bf16_t)v.w;
        ((bf16x4*)(mbf + (size_t)r*TGT))[t] = o;
        psq = v.x*v.x + v.y*v.y + v.z*v.z + v.w*v.w;
    } else {
        bf16x4 z; z[0] = z[1] = z[2] = z[3] = (bf16_t)0.f;
        ((bf16x4*)(mbf + (size_t)r*TGT))[t] = z;
    }
    for (int off = 32; off > 0; off >>= 1) psq += __shfl_down(psq, off, 64);
    if ((t & 63) == 0) red[t >> 6] = psq;
    __syncthreads();
    if (t == 0) mnorm[r] = (r < NMEM) ? ((red[0]+red[1])+(red[2]+red[3])) : 1e30f;
}

__global__ void init_kernel(int* __restrict__ p)
{
    int i = blockIdx.x*256 + threadIdx.x;
    if (i < NPATCH) p[i] = 0x7f7f7f7f;
}

// ---------------------------------------------------------------------------
// Kernel B: fused GEMM + min. 256x256 tile, 8 waves (2Mx4N), 512 threads.
// Deep pipeline: 4 LDS buffers over BK=32 K-tiles (4 x 32 KB = 128 KB),
// staging 3 K-tiles ahead with counted s_waitcnt vmcnt(4) + raw s_barrier
// (never a full drain in the main loop). A-fragments are read one K-tile
// ahead into an alternating register set (aE/aO) so ds_read latency hides
// under the 32-MFMA block. XOR k-group swizzle kept from the 128^2 version
// (global-side swizzle for linear global_load_lds dest; un-applied at
// fragment read) -> conflict-free ds_read_b128.
//
// Safety invariants:
//  * STAGE(t+3) overwrites buf[(t+3)&3] = tile t-1's buffer; all reads of
//    tile t-1 completed before the end-of-(t-1) lgkmcnt(0)+barrier.
//  * end-of-iter vmcnt(4) leaves only STAGE(t+3)'s 4 loads in flight ->
//    tile t+2 (the 4 oldest outstanding) is guaranteed landed before the
//    barrier; any extra VMEM ops (spills) only make this MORE conservative.
// ---------------------------------------------------------------------------
__device__ __forceinline__ void load_lds16(const void* g, void* l)
{
    __builtin_amdgcn_global_load_lds(
        (__attribute__((address_space(1))) void*)g,
        (__attribute__((address_space(3))) void*)l, 16, 0, 0);
}

#define SYNC_V(N) do { \
    asm volatile("s_waitcnt vmcnt(" #N ") lgkmcnt(0)" ::: "memory"); \
    __builtin_amdgcn_s_barrier(); } while (0)

__global__ __launch_bounds__(512, 2) void nnmin_kernel(
    const bf16_t* __restrict__ E, const bf16_t* __restrict__ M,
    const float* __restrict__ enorm, const float* __restrict__ mnorm,
    int* __restrict__ out_min)
{
    __shared__ __attribute__((aligned(16))) bf16_t SA[4][256*32];   // 64 KB
    __shared__ __attribute__((aligned(16))) bf16_t SB[4][256*32];   // 64 KB

    const int m0   = blockIdx.x * 256;
    const int n0   = blockIdx.y * 256;
    const int tid  = threadIdx.x;
    const int lane = tid & 63;
    const int wave = tid >> 6;
    const int wm   = wave >> 2;      // 0..1  (M half)
    const int wn   = wave & 3;       // 0..3  (N quarter)

    // staging: thread -> (row, 16B slot); swizzled k-group on the global side
    const int srow = tid >> 2;       // 0..127
    const int slot = tid & 3;
    const int kg   = slot ^ ((srow >> 1) & 3);

    const bf16_t* gA0 = E + (size_t)(m0 + srow)*TGT + kg*8;
    const bf16_t* gA1 = gA0 + (size_t)128*TGT;
    const bf16_t* gB0 = M + (size_t)(n0 + srow)*TGT + kg*8;
    const bf16_t* gB1 = gB0 + (size_t)128*TGT;
    const int lofs = tid * 8;        // linear LDS dest (wave base + lane*16B)

    // fragment-read offsets (un-swizzle at read)
    const int fr = lane & 15;
    const int fg = lane >> 4;
    int aoff[8], boff[4];
#pragma unroll
    for (int tm = 0; tm < 8; ++tm) {
        const int row = wm*128 + tm*16 + fr;
        aoff[tm] = row*32 + (fg ^ ((row >> 1) & 3))*8;
    }
#pragma unroll
    for (int tn = 0; tn < 4; ++tn) {
        const int row = wn*64 + tn*16 + fr;
        boff[tn] = row*32 + (fg ^ ((row >> 1) & 3))*8;
    }

    floatx4 acc[8][4];
#pragma unroll
    for (int i = 0; i < 8; ++i)
#pragma unroll
        for (int j = 0; j < 4; ++j) acc[i][j] = (floatx4)0.0f;

#define STAGE(t) do { \
    bf16_t* _a = &SA[(t)&3][lofs]; \
    bf16_t* _b = &SB[(t)&3][lofs]; \
    const int _ko = (t)*32; \
    load_lds16(gA0 + _ko, _a); \
    load_lds16(gA1 + _ko, _a + 4096); \
    load_lds16(gB0 + _ko, _b); \
    load_lds16(gB1 + _ko, _b + 4096); } while (0)

#define READ_A(t, A_) do { const bf16_t* _p = SA[(t)&3]; \
    _Pragma("unroll") \
    for (int _m = 0; _m < 8; ++_m) A_[_m] = *(const bf16x8*)(_p + aoff[_m]); } while (0)

#define READ_B(t, B_) do { const bf16_t* _p = SB[(t)&3]; \
    _Pragma("unroll") \
    for (int _n = 0; _n < 4; ++_n) B_[_n] = *(const bf16x8*)(_p + boff[_n]); } while (0)

#define MFMA_ALL(A_, B_) do { \
    __builtin_amdgcn_s_setprio(1); \
    _Pragma("unroll") \
    for (int _m = 0; _m < 8; ++_m) \
    _Pragma("unroll") \
    for (int _n = 0; _n < 4; ++_n) \
        acc[_m][_n] = __builtin_amdgcn_mfma_f32_16x16x32_bf16(A_[_m], B_[_n], acc[_m][_n], 0, 0, 0); \
    __builtin_amdgcn_s_setprio(0); } while (0)

    bf16x8 aE[8], aO[8], bb[4];

    // prologue: tiles 0,1,2 staged; ensure 0,1 landed (2 stays in flight)
    STAGE(0); STAGE(1); STAGE(2);
    asm volatile("s_waitcnt vmcnt(4)" ::: "memory");
    __builtin_amdgcn_s_barrier();
    READ_A(0, aE);

    // steady state: 14 pairs covering K-tiles 0..27
    for (int t = 0; t < 28; t += 2) {
        STAGE(t+3);
        READ_B(t,   bb);
        READ_A(t+1, aO);
        MFMA_ALL(aE, bb);
        SYNC_V(4);
        STAGE(t+4);
        READ_B(t+1, bb);
        READ_A(t+2, aE);
        MFMA_ALL(aO, bb);
        SYNC_V(4);
    }
    // drain: tiles 28..31
    STAGE(31); READ_B(28, bb); READ_A(29, aO); MFMA_ALL(aE, bb); SYNC_V(4);
               READ_B(29, bb); READ_A(30, aE); MFMA_ALL(aO, bb); SYNC_V(0);
               READ_B(30, bb); READ_A(31, aO); MFMA_ALL(aE, bb);
               READ_B(31, bb);                 MFMA_ALL(aO, bb);

#undef STAGE
#undef READ_A
#undef READ_B
#undef MFMA_ALL

    // epilogue: d2 + min over this block's 256 columns, atomicMin per row
    float mn[4];
#pragma unroll
    for (int tn = 0; tn < 4; ++tn)
        mn[tn] = mnorm[n0 + wn*64 + tn*16 + fr];
    const int rowq = fg * 4;
#pragma unroll
    for (int tm = 0; tm < 8; ++tm) {
#pragma unroll
        for (int r = 0; r < 4; ++r) {
            const int row = m0 + wm*128 + tm*16 + rowq + r;
            const float en = enorm[row];
            float best = 1e38f;
#pragma unroll
            for (int tn = 0; tn < 4; ++tn)
                best = fminf(best, en + mn[tn] - 2.0f*acc[tm][tn][r]);
#pragma unroll
            for (int off = 1; off < 16; off <<= 1)
                best = fminf(best, __shfl_xor(best, off, 64));
            if (fr == 0)
                atomicMin(&out_min[row], __float_as_int(best));
        }
    }
}

// ---------------------------------------------------------------------------
// Kernel C1: image scores = max over 576 patches per batch
// ---------------------------------------------------------------------------
__global__ __launch_bounds__(256) void score_kernel(
    const int* __restrict__ ps_bits, float* __restrict__ out)
{
    const int b = blockIdx.x, tid = threadIdx.x;
    __shared__ float red[4];
    float m = -1e38f;
    for (int i = tid; i < GRID_*GRID_; i += 256)
        m = fmaxf(m, __int_as_float(ps_bits[b*GRID_*GRID_ + i]));
    for (int off = 32; off > 0; off >>= 1) m = fmaxf(m, __shfl_down(m, off, 64));
    if ((tid & 63) == 0) red[tid >> 6] = m;
    __syncthreads();
    if (tid == 0) out[b] = fmaxf(fmaxf(red[0], red[1]), fmaxf(red[2], red[3]));
}

// ---------------------------------------------------------------------------
// Kernel C2: bilinear 24x24 -> 384x384 (jax half-pixel == clamped bilinear)
// ---------------------------------------------------------------------------
__global__ __launch_bounds__(256) void mask_kernel(
    const int* __restrict__ ps_bits, float* __restrict__ masks)
{
    int idx = blockIdx.x*256 + threadIdx.x;
    int b  = idx / (IMG_*IMG_);
    int p  = idx - b*(IMG_*IMG_);
    int oy = p / IMG_, ox = p - oy*IMG_;

    float fy = (oy + 0.5f) * (1.0f/16.0f) - 0.5f;
    float fx = (ox + 0.5f) * (1.0f/16.0f) - 0.5f;
    int y0 = (int)floorf(fy); float ty = fy - (float)y0;
    int x0 = (int)floorf(fx); float tx = fx - (float)x0;
    int y0c = min(max(y0, 0), GRID_-1), y1c = min(max(y0+1, 0), GRID_-1);
    int x0c = min(max(x0, 0), GRID_-1), x1c = min(max(x0+1, 0), GRID_-1);

    const int* psb = ps_bits + b*GRID_*GRID_;
    float v00 = __int_as_float(psb[y0c*GRID_ + x0c]);
    float v01 = __int_as_float(psb[y0c*GRID_ + x1c]);
    float v10 = __int_as_float(psb[y1c*GRID_ + x0c]);
    float v11 = __int_as_float(psb[y1c*GRID_ + x1c]);
    float v0 = v00 + (v01 - v00)*tx;
    float v1 = v10 + (v11 - v10)*tx;
    masks[idx] = v0 + (v1 - v0)*ty;
}

// ---------------------------------------------------------------------------
extern "C" void kernel_launch(void* const* d_in, const int* in_sizes, int n_in,
                              void* d_out, int out_size, void* d_ws, size_t ws_size,
                              hipStream_t stream)
{
    const float* f6  = (const float*)d_in[0];
    const float* f8  = (const float*)d_in[1];
    const float* f10 = (const float*)d_in[2];
    const float* mb  = (const float*)d_in[3];
    float* out = (float*)d_out;

    char* ws = (char*)d_ws;
    bf16_t* emb  = (bf16_t*)ws;  ws += (size_t)NPATCH*TGT*sizeof(bf16_t);
    bf16_t* mbf  = (bf16_t*)ws;  ws += (size_t)NMEM_PAD*TGT*sizeof(bf16_t);
    float* enorm = (float*)ws;   ws += (size_t)NPATCH*sizeof(float);
    float* mnorm = (float*)ws;   ws += (size_t)NMEM_PAD*sizeof(float);
    int* psbits  = (int*)ws;     ws += (size_t)NPATCH*sizeof(int);

    hipLaunchKernelGGL(emb_kernel, dim3(NPATCH), dim3(256), 0, stream,
                       f6, f8, f10, emb, enorm);
    hipLaunchKernelGGL(mprep_kernel, dim3(NMEM_PAD), dim3(256), 0, stream,
                       mb, mbf, mnorm);
    hipLaunchKernelGGL(init_kernel, dim3((NPATCH+255)/256), dim3(256), 0, stream,
                       psbits);
    hipLaunchKernelGGL(nnmin_kernel, dim3(NPATCH/256, NMEM_PAD/256), dim3(512),
                       0, stream, emb, mbf, enorm, mnorm, psbits);
    hipLaunchKernelGGL(score_kernel, dim3(B_), dim3(256), 0, stream,
                       psbits, out);
    hipLaunchKernelGGL(mask_kernel, dim3((B_*IMG_*IMG_)/256), dim3(256), 0, stream,
                       psbits, out + B_);
}

// Round 2
// 429.643 us; speedup vs baseline: 1.0942x; 1.0942x over previous
//
#include <hip/hip_runtime.h>
#include <hip/hip_bf16.h>
#include <stdint.h>

#define B_      8
#define GRID_   24
#define C_      768
#define NPATCH  (B_*GRID_*GRID_)   // 4608
#define PRE     1024
#define TGT     1024
#define NMEM    20000
#define NMEM_PAD 20224             // 79 * 256
#define IMG_    384
#define SEQ     577                // GRID*GRID + 1

typedef __bf16 bf16_t;
typedef bf16_t bf16x8 __attribute__((ext_vector_type(8)));
typedef bf16_t bf16x4 __attribute__((ext_vector_type(4)));
typedef float  floatx4 __attribute__((ext_vector_type(4)));

// ---------------------------------------------------------------------------
// Kernel A: per-patch pooled embedding, register-direct.
// ---------------------------------------------------------------------------
__global__ __launch_bounds__(256) void emb_kernel(
    const float* __restrict__ f6, const float* __restrict__ f8,
    const float* __restrict__ f10,
    bf16_t* __restrict__ emb, float* __restrict__ enorm)
{
    __shared__ float pooled[3*PRE];   // 12 KB
    __shared__ float red[4];

    const int n   = blockIdx.x;
    const int b   = n / (GRID_*GRID_);
    const int yx  = n - b*(GRID_*GRID_);
    const int y   = yx / GRID_;
    const int x   = yx - y*GRID_;
    const int t   = threadIdx.x;

    const float* fl[3] = {f6, f8, f10};

#pragma unroll
    for (int l = 0; l < 3; ++l) {
        const float* f = fl[l];
        float A0 = 0.f, B0 = 0.f, C1 = 0.f, D1 = 0.f, E2 = 0.f, F2 = 0.f;
#pragma unroll
        for (int k = 0; k < 9; ++k) {
            const int kh = k / 3, kw = k - kh*3;
            const int ny = y + kh - 1, nx = x + kw - 1;
            const bool v = (ny >= 0 && ny < GRID_ && nx >= 0 && nx < GRID_);
            const int off = v ? (b*SEQ + 1 + ny*GRID_ + nx) : (b*SEQ);
            const float* p = f + (size_t)off*C_ + 3*t;
            float a = p[0], bq = p[1], c = p[2];
            if (!v) { a = 0.f; bq = 0.f; c = 0.f; }
            if (k <= 6) A0 += a;
            if (k >= 6) B0 += a;
            if (k <= 4) C1 += bq;
            if (k >= 4) D1 += bq;
            if (k <= 2) E2 += c;
            if (k >= 2) F2 += c;
        }
        float4 pv;
        pv.x = A0 * (1.f/7.f);
        pv.y = (B0 + C1) * (1.f/8.f);
        pv.z = (D1 + E2) * (1.f/8.f);
        pv.w = F2 * (1.f/7.f);
        *(float4*)(pooled + l*PRE + 4*t) = pv;
    }
    __syncthreads();

    float psq = 0.f;
    bf16x4 ev;
#pragma unroll
    for (int r = 0; r < 4; ++r) {
        const int j = 4*t + r;
        float vv = (pooled[3*j] + pooled[3*j+1] + pooled[3*j+2]) * (1.f/3.f);
        ev[r] = (bf16_t)vv;
        psq += vv*vv;
    }
    *(bf16x4*)(emb + (size_t)n*TGT + 4*t) = ev;

    for (int off = 32; off > 0; off >>= 1) psq += __shfl_down(psq, off, 64);
    if ((t & 63) == 0) red[t >> 6] = psq;
    __syncthreads();
    if (t == 0) enorm[n] = (red[0] + red[1]) + (red[2] + red[3]);
}

// ---------------------------------------------------------------------------
// Kernel M: memory_bank fp32 -> bf16 (padded rows zeroed) + ||m||^2, float4.
// ---------------------------------------------------------------------------
__global__ __launch_bounds__(256) void mprep_kernel(
    const float* __restrict__ mb, bf16_t* __restrict__ mbf,
    float* __restrict__ mnorm)
{
    const int r = blockIdx.x;
    const int t = threadIdx.x;
    __shared__ float red[4];
    float psq = 0.f;
    if (r < NMEM) {
        float4 v = ((const float4*)(mb + (size_t)r*TGT))[t];
        bf16x4 o;
        o[0] = (bf16_t)v.x; o[1] = (bf16_t)v.y;
        o[2] = (bf16_t)v.z; o[3] = (bf16_t)v.w;
        ((bf16x4*)(mbf + (size_t)r*TGT))[t] = o;
        psq = v.x*v.x + v.y*v.y + v.z*v.z + v.w*v.w;
    } else {
        bf16x4 z; z[0] = z[1] = z[2] = z[3] = (bf16_t)0.f;
        ((bf16x4*)(mbf + (size_t)r*TGT))[t] = z;
    }
    for (int off = 32; off > 0; off >>= 1) psq += __shfl_down(psq, off, 64);
    if ((t & 63) == 0) red[t >> 6] = psq;
    __syncthreads();
    if (t == 0) mnorm[r] = (r < NMEM) ? ((red[0]+red[1])+(red[2]+red[3])) : 1e30f;
}

__global__ void init_kernel(int* __restrict__ p)
{
    int i = blockIdx.x*256 + threadIdx.x;
    if (i < NPATCH) p[i] = 0x7f7f7f7f;
}

// ---------------------------------------------------------------------------
// Kernel B: fused GEMM + min, 256x256 tile, BK=64, 8 waves, 4-phase schedule
// (port of the verified 256^2 8-phase template, m198/m201).
//
// LDS: 2 buffers x (A 32KB + B 32KB) = 128 KB. XOR swizzle: LDS 16B-slot s of
// row r holds global k-group s ^ (r&7); inverse swizzle applied on the GLOBAL
// source address (linear global_load_lds dest), un-applied at ds_read.
// -> free 2-way bank conflicts on ds_read_b128.
//
// Per K-tile t, 4 phases, each {ds_read subtile | stage 1 half-tile | barrier;
// lgkmcnt(0); setprio(1); 16 MFMA; setprio(0); barrier}:
//   ph0: read a[0..3],b[0..1] (12) | stage A-lo(t+1) | MFMA Q(0,0)
//   ph1: read b[2..3]         (4)  | stage A-hi(t+1) | MFMA Q(0,1)
//   ph2: read a[4..7]         (8)  | stage B-lo(t+2) | MFMA Q(1,0)
//   ph3: (no reads)                | stage B-hi(t+2) | vmcnt(4); MFMA Q(1,1)
//
// vmcnt(4) proof: at ph3 the 12 outstanding loads (issue order) are
// [B(t+1) x4 (prev tile ph2/ph3), A(t+1) x4 (ph0/ph1), B(t+2) x4 (ph2/ph3)];
// waiting to 4 completes everything except B(t+2) -> ALL of tile t+1 is
// landed before tile t+1 ph0 reads it. No vmcnt(0) in the loop.
// Region reuse: each half-tile region is overwritten >=1 full phase (with
// lgkmcnt(0)+barrier) after its last ds_read drains.
// ---------------------------------------------------------------------------
__device__ __forceinline__ void load_lds16(const void* g, void* l)
{
    __builtin_amdgcn_global_load_lds(
        (__attribute__((address_space(1))) void*)g,
        (__attribute__((address_space(3))) void*)l, 16, 0, 0);
}

#define BAR()   do { asm volatile("" ::: "memory"); \
                     __builtin_amdgcn_s_barrier(); \
                     asm volatile("" ::: "memory"); } while (0)
#define LGKM0() asm volatile("s_waitcnt lgkmcnt(0)" ::: "memory")
#define VM4()   asm volatile("s_waitcnt vmcnt(4)" ::: "memory")

__global__ __launch_bounds__(512, 2) void nnmin_kernel(
    const bf16_t* __restrict__ E, const bf16_t* __restrict__ M,
    const float* __restrict__ enorm, const float* __restrict__ mnorm,
    int* __restrict__ out_min)
{
    __shared__ __attribute__((aligned(16))) bf16_t SA[2][256*64];   // 64 KB
    __shared__ __attribute__((aligned(16))) bf16_t SB[2][256*64];   // 64 KB

    const int m0   = blockIdx.x * 256;
    const int n0   = blockIdx.y * 256;
    const int tid  = threadIdx.x;
    const int lane = tid & 63;
    const int wave = tid >> 6;
    const int wm   = wave >> 2;      // 0..1  (M half)
    const int wn   = wave & 3;       // 0..3  (N quarter)
    const int fr   = lane & 15;
    const int fg   = lane >> 4;

    // staging geometry: thread covers (row grow + j*64, slot tid&7);
    // fetches k-group gks = slot ^ (row&7)  (j*64 preserves row&7)
    const int grow = tid >> 3;                  // 0..63
    const int gks  = (tid & 7) ^ (grow & 7);
    const int lofs = tid * 8;                   // bf16 units per batch

    const bf16_t* pA = E + (size_t)(m0 + grow)*TGT + gks*8;
    const bf16_t* pB = M + (size_t)(n0 + grow)*TGT + gks*8;

    // fragment-read swizzled slots (row&7 == fr&7 since row bases are x16)
    const int xs0  = (fg)     ^ (fr & 7);       // kk = 0
    const int xs1  = (4 + fg) ^ (fr & 7);       // kk = 1
    const int arow = (wm*128 + fr) * 64;        // bf16 units
    const int brow = (wn*64  + fr) * 64;

    floatx4 acc[8][4];
#pragma unroll
    for (int i = 0; i < 8; ++i)
#pragma unroll
        for (int j = 0; j < 4; ++j) acc[i][j] = (floatx4)0.0f;

#define STG_A(buf, tk, j) load_lds16(pA + (size_t)(j)*64*TGT + (tk)*64, \
                                     &SA[buf][(j)*4096 + lofs])
#define STG_B(buf, tk, j) load_lds16(pB + (size_t)(j)*64*TGT + (tk)*64, \
                                     &SB[buf][(j)*4096 + lofs])

#define RD_A(buf, mh, A_) do { \
    _Pragma("unroll") \
    for (int _m = 0; _m < 4; ++_m) { \
        A_[_m][0] = *(const bf16x8*)&SA[buf][arow + ((mh)*4+_m)*1024 + xs0*8]; \
        A_[_m][1] = *(const bf16x8*)&SA[buf][arow + ((mh)*4+_m)*1024 + xs1*8]; } } while (0)

#define RD_B(buf, nh, B_) do { \
    _Pragma("unroll") \
    for (int _n = 0; _n < 2; ++_n) { \
        B_[_n][0] = *(const bf16x8*)&SB[buf][brow + ((nh)*2+_n)*1024 + xs0*8]; \
        B_[_n][1] = *(const bf16x8*)&SB[buf][brow + ((nh)*2+_n)*1024 + xs1*8]; } } while (0)

#define MFMA16(mh, nh, A_, B_) do { \
    __builtin_amdgcn_s_setprio(1); \
    _Pragma("unroll") \
    for (int _m = 0; _m < 4; ++_m) \
    _Pragma("unroll") \
    for (int _n = 0; _n < 2; ++_n) { \
        acc[(mh)*4+_m][(nh)*2+_n] = __builtin_amdgcn_mfma_f32_16x16x32_bf16( \
            A_[_m][0], B_[_n][0], acc[(mh)*4+_m][(nh)*2+_n], 0, 0, 0); \
        acc[(mh)*4+_m][(nh)*2+_n] = __builtin_amdgcn_mfma_f32_16x16x32_bf16( \
            A_[_m][1], B_[_n][1], acc[(mh)*4+_m][(nh)*2+_n], 0, 0, 0); } \
    __builtin_amdgcn_s_setprio(0); } while (0)

#define TILE(bufc, bufn, tkA, tkB) do { \
    RD_A(bufc, 0, aa); RD_B(bufc, 0, bb); \
    STG_A(bufn, tkA, 0); STG_A(bufn, tkA, 1); \
    BAR(); LGKM0(); MFMA16(0, 0, aa, bb); BAR(); \
    RD_B(bufc, 1, bc); \
    STG_A(bufn, tkA, 2); STG_A(bufn, tkA, 3); \
    BAR(); LGKM0(); MFMA16(0, 1, aa, bc); BAR(); \
    RD_A(bufc, 1, aa); \
    STG_B(bufc, tkB, 0); STG_B(bufc, tkB, 1); \
    BAR(); LGKM0(); MFMA16(1, 0, aa, bb); BAR(); \
    STG_B(bufc, tkB, 2); STG_B(bufc, tkB, 3); \
    VM4(); BAR(); MFMA16(1, 1, aa, bc); BAR(); \
} while (0)

    bf16x8 aa[4][2], bb[2][2], bc[2][2];

    // prologue: A(0),B(0) -> buf0 (8 loads), B(1) -> buf1 (4 loads);
    // vmcnt(4) -> tile 0 fully landed, B(1) in flight = steady-state entry.
#pragma unroll
    for (int j = 0; j < 4; ++j) STG_A(0, 0, j);
#pragma unroll
    for (int j = 0; j < 4; ++j) STG_B(0, 0, j);
#pragma unroll
    for (int j = 0; j < 4; ++j) STG_B(1, 1, j);
    VM4(); BAR();

    for (int t = 0; t < 16; t += 2) {
        const int a0 = t + 1;                       // <= 15 always (t even <=14)
        const int b0 = (t + 2 < 16) ? t + 2 : 15;   // clamp: dummy re-stage
        TILE(0, 1, a0, b0);
        const int a1 = (t + 2 < 16) ? t + 2 : 15;
        const int b1 = (t + 3 < 16) ? t + 3 : 15;
        TILE(1, 0, a1, b1);
    }

#undef STG_A
#undef STG_B
#undef RD_A
#undef RD_B
#undef MFMA16
#undef TILE

    // epilogue: d2 + min over this block's 256 columns, atomicMin per row
    float mn[4];
#pragma unroll
    for (int tn = 0; tn < 4; ++tn)
        mn[tn] = mnorm[n0 + wn*64 + tn*16 + fr];
    const int rowq = fg * 4;
#pragma unroll
    for (int tm = 0; tm < 8; ++tm) {
#pragma unroll
        for (int r = 0; r < 4; ++r) {
            const int row = m0 + wm*128 + tm*16 + rowq + r;
            const float en = enorm[row];
            float best = 1e38f;
#pragma unroll
            for (int tn = 0; tn < 4; ++tn)
                best = fminf(best, en + mn[tn] - 2.0f*acc[tm][tn][r]);
#pragma unroll
            for (int off = 1; off < 16; off <<= 1)
                best = fminf(best, __shfl_xor(best, off, 64));
            if (fr == 0)
                atomicMin(&out_min[row], __float_as_int(best));
        }
    }
}

// ---------------------------------------------------------------------------
// Kernel C1: image scores = max over 576 patches per batch
// ---------------------------------------------------------------------------
__global__ __launch_bounds__(256) void score_kernel(
    const int* __restrict__ ps_bits, float* __restrict__ out)
{
    const int b = blockIdx.x, tid = threadIdx.x;
    __shared__ float red[4];
    float m = -1e38f;
    for (int i = tid; i < GRID_*GRID_; i += 256)
        m = fmaxf(m, __int_as_float(ps_bits[b*GRID_*GRID_ + i]));
    for (int off = 32; off > 0; off >>= 1) m = fmaxf(m, __shfl_down(m, off, 64));
    if ((tid & 63) == 0) red[tid >> 6] = m;
    __syncthreads();
    if (tid == 0) out[b] = fmaxf(fmaxf(red[0], red[1]), fmaxf(red[2], red[3]));
}

// ---------------------------------------------------------------------------
// Kernel C2: bilinear 24x24 -> 384x384 (jax half-pixel == clamped bilinear)
// ---------------------------------------------------------------------------
__global__ __launch_bounds__(256) void mask_kernel(
    const int* __restrict__ ps_bits, float* __restrict__ masks)
{
    int idx = blockIdx.x*256 + threadIdx.x;
    int b  = idx / (IMG_*IMG_);
    int p  = idx - b*(IMG_*IMG_);
    int oy = p / IMG_, ox = p - oy*IMG_;

    float fy = (oy + 0.5f) * (1.0f/16.0f) - 0.5f;
    float fx = (ox + 0.5f) * (1.0f/16.0f) - 0.5f;
    int y0 = (int)floorf(fy); float ty = fy - (float)y0;
    int x0 = (int)floorf(fx); float tx = fx - (float)x0;
    int y0c = min(max(y0, 0), GRID_-1), y1c = min(max(y0+1, 0), GRID_-1);
    int x0c = min(max(x0, 0), GRID_-1), x1c = min(max(x0+1, 0), GRID_-1);

    const int* psb = ps_bits + b*GRID_*GRID_;
    float v00 = __int_as_float(psb[y0c*GRID_ + x0c]);
    float v01 = __int_as_float(psb[y0c*GRID_ + x1c]);
    float v10 = __int_as_float(psb[y1c*GRID_ + x0c]);
    float v11 = __int_as_float(psb[y1c*GRID_ + x1c]);
    float v0 = v00 + (v01 - v00)*tx;
    float v1 = v10 + (v11 - v10)*tx;
    masks[idx] = v0 + (v1 - v0)*ty;
}

// ---------------------------------------------------------------------------
extern "C" void kernel_launch(void* const* d_in, const int* in_sizes, int n_in,
                              void* d_out, int out_size, void* d_ws, size_t ws_size,
                              hipStream_t stream)
{
    const float* f6  = (const float*)d_in[0];
    const float* f8  = (const float*)d_in[1];
    const float* f10 = (const float*)d_in[2];
    const float* mb  = (const float*)d_in[3];
    float* out = (float*)d_out;

    char* ws = (char*)d_ws;
    bf16_t* emb  = (bf16_t*)ws;  ws += (size_t)NPATCH*TGT*sizeof(bf16_t);
    bf16_t* mbf  = (bf16_t*)ws;  ws += (size_t)NMEM_PAD*TGT*sizeof(bf16_t);
    float* enorm = (float*)ws;   ws += (size_t)NPATCH*sizeof(float);
    float* mnorm = (float*)ws;   ws += (size_t)NMEM_PAD*sizeof(float);
    int* psbits  = (int*)ws;     ws += (size_t)NPATCH*sizeof(int);

    hipLaunchKernelGGL(emb_kernel, dim3(NPATCH), dim3(256), 0, stream,
                       f6, f8, f10, emb, enorm);
    hipLaunchKernelGGL(mprep_kernel, dim3(NMEM_PAD), dim3(256), 0, stream,
                       mb, mbf, mnorm);
    hipLaunchKernelGGL(init_kernel, dim3((NPATCH+255)/256), dim3(256), 0, stream,
                       psbits);
    hipLaunchKernelGGL(nnmin_kernel, dim3(NPATCH/256, NMEM_PAD/256), dim3(512),
                       0, stream, emb, mbf, enorm, mnorm, psbits);
    hipLaunchKernelGGL(score_kernel, dim3(B_), dim3(256), 0, stream,
                       psbits, out);
    hipLaunchKernelGGL(mask_kernel, dim3((B_*IMG_*IMG_)/256), dim3(256), 0, stream,
                       psbits, out + B_);
}

// Round 3
// 419.749 us; speedup vs baseline: 1.1200x; 1.0236x over previous
//
#include <hip/hip_runtime.h>
#include <hip/hip_bf16.h>
#include <stdint.h>

#define B_      8
#define GRID_   24
#define C_      768
#define NPATCH  (B_*GRID_*GRID_)   // 4608
#define PRE     1024
#define TGT     1024
#define NMEM    20000
#define NMEM_PAD 20224             // 79 * 256
#define IMG_    384
#define SEQ     577                // GRID*GRID + 1
#define GM      (NPATCH/256)       // 18
#define GN      (NMEM_PAD/256)     // 79

typedef __bf16 bf16_t;
typedef bf16_t bf16x8 __attribute__((ext_vector_type(8)));
typedef bf16_t bf16x4 __attribute__((ext_vector_type(4)));
typedef float  floatx4 __attribute__((ext_vector_type(4)));

// ---------------------------------------------------------------------------
// Kernel P (fused): blocks [0, NPATCH) do per-patch pooled embedding (+psbits
// init); blocks [NPATCH, NPATCH+NMEM_PAD/4) do memory-bank prep, one row per
// wave (no LDS, no barriers). Single launch replaces emb+mprep+init.
// ---------------------------------------------------------------------------
__global__ __launch_bounds__(256) void prep_kernel(
    const float* __restrict__ f6, const float* __restrict__ f8,
    const float* __restrict__ f10, const float* __restrict__ mb,
    bf16_t* __restrict__ emb, float* __restrict__ enorm,
    bf16_t* __restrict__ mbf, float* __restrict__ mnorm,
    int* __restrict__ psbits)
{
    __shared__ float pooled[3*PRE];   // 12 KB (emb path only)
    __shared__ float red[4];

    const int t = threadIdx.x;

    if (blockIdx.x >= NPATCH) {
        // ---- memory-bank prep: one row per wave ----
        const int rbase = (blockIdx.x - NPATCH) * 4;
        const int w     = t >> 6;
        const int lane  = t & 63;
        const int row   = rbase + w;
        float psq = 0.f;
        if (row < NMEM) {
            const float4* src = (const float4*)(mb + (size_t)row*TGT);
            bf16x4*       dst = (bf16x4*)(mbf + (size_t)row*TGT);
#pragma unroll
            for (int j = 0; j < 4; ++j) {
                float4 v = src[j*64 + lane];
                bf16x4 o;
                o[0] = (bf16_t)v.x; o[1] = (bf16_t)v.y;
                o[2] = (bf16_t)v.z; o[3] = (bf16_t)v.w;
                dst[j*64 + lane] = o;
                psq += v.x*v.x + v.y*v.y + v.z*v.z + v.w*v.w;
            }
        } else {
            bf16x4 z; z[0] = z[1] = z[2] = z[3] = (bf16_t)0.f;
            bf16x4* dst = (bf16x4*)(mbf + (size_t)row*TGT);
#pragma unroll
            for (int j = 0; j < 4; ++j) dst[j*64 + lane] = z;
        }
        for (int off = 32; off > 0; off >>= 1) psq += __shfl_down(psq, off, 64);
        if (lane == 0) mnorm[row] = (row < NMEM) ? psq : 1e30f;
        return;
    }

    // ---- per-patch pooled embedding ----
    const int n   = blockIdx.x;
    const int b   = n / (GRID_*GRID_);
    const int yx  = n - b*(GRID_*GRID_);
    const int y   = yx / GRID_;
    const int x   = yx - y*GRID_;

    if (t == 0) psbits[n] = 0x7f7f7f7f;   // init for nnmin atomicMin

    const float* fl[3] = {f6, f8, f10};

#pragma unroll
    for (int l = 0; l < 3; ++l) {
        const float* f = fl[l];
        float A0 = 0.f, B0 = 0.f, C1 = 0.f, D1 = 0.f, E2 = 0.f, F2 = 0.f;
#pragma unroll
        for (int k = 0; k < 9; ++k) {
            const int kh = k / 3, kw = k - kh*3;
            const int ny = y + kh - 1, nx = x + kw - 1;
            const bool v = (ny >= 0 && ny < GRID_ && nx >= 0 && nx < GRID_);
            const int off = v ? (b*SEQ + 1 + ny*GRID_ + nx) : (b*SEQ);
            const float* p = f + (size_t)off*C_ + 3*t;
            float a = p[0], bq = p[1], c = p[2];
            if (!v) { a = 0.f; bq = 0.f; c = 0.f; }
            if (k <= 6) A0 += a;
            if (k >= 6) B0 += a;
            if (k <= 4) C1 += bq;
            if (k >= 4) D1 += bq;
            if (k <= 2) E2 += c;
            if (k >= 2) F2 += c;
        }
        float4 pv;
        pv.x = A0 * (1.f/7.f);
        pv.y = (B0 + C1) * (1.f/8.f);
        pv.z = (D1 + E2) * (1.f/8.f);
        pv.w = F2 * (1.f/7.f);
        *(float4*)(pooled + l*PRE + 4*t) = pv;
    }
    __syncthreads();

    float psq = 0.f;
    bf16x4 ev;
#pragma unroll
    for (int r = 0; r < 4; ++r) {
        const int j = 4*t + r;
        float vv = (pooled[3*j] + pooled[3*j+1] + pooled[3*j+2]) * (1.f/3.f);
        ev[r] = (bf16_t)vv;
        psq += vv*vv;
    }
    *(bf16x4*)(emb + (size_t)n*TGT + 4*t) = ev;

    for (int off = 32; off > 0; off >>= 1) psq += __shfl_down(psq, off, 64);
    if ((t & 63) == 0) red[t >> 6] = psq;
    __syncthreads();
    if (t == 0) enorm[n] = (red[0] + red[1]) + (red[2] + red[3]);
}

// ---------------------------------------------------------------------------
// Kernel B: fused GEMM + min, 256x256 tile, BK=64, 8 waves, 4-phase schedule
// with counted vmcnt (structure unchanged from round 2 — best so far).
// NEW: bijective XCD chunk swizzle (m204) on the linear block id so that each
// XCD owns a contiguous run of ~178 n-major ids (~10 full n0-panels) -> the
// 512 KB B-panel stays hot in that XCD's L2 instead of being re-fetched from
// HBM by all 8 XCDs.
// ---------------------------------------------------------------------------
__device__ __forceinline__ void load_lds16(const void* g, void* l)
{
    __builtin_amdgcn_global_load_lds(
        (__attribute__((address_space(1))) void*)g,
        (__attribute__((address_space(3))) void*)l, 16, 0, 0);
}

#define BAR()   do { asm volatile("" ::: "memory"); \
                     __builtin_amdgcn_s_barrier(); \
                     asm volatile("" ::: "memory"); } while (0)
#define LGKM0() asm volatile("s_waitcnt lgkmcnt(0)" ::: "memory")
#define VM4()   asm volatile("s_waitcnt vmcnt(4)" ::: "memory")

__global__ __launch_bounds__(512, 2) void nnmin_kernel(
    const bf16_t* __restrict__ E, const bf16_t* __restrict__ M,
    const float* __restrict__ enorm, const float* __restrict__ mnorm,
    int* __restrict__ out_min)
{
    __shared__ __attribute__((aligned(16))) bf16_t SA[2][256*64];   // 64 KB
    __shared__ __attribute__((aligned(16))) bf16_t SB[2][256*64];   // 64 KB

    // ---- bijective XCD chunk swizzle (nwg = 18*79 = 1422, NXCD = 8) ----
    const int orig = blockIdx.y * GM + blockIdx.x;   // n-major: 18 ids share n0
    const int q    = (GM*GN) >> 3;                   // 177
    const int r    = (GM*GN) & 7;                    // 6
    const int xcd  = orig & 7;
    const int pos  = orig >> 3;
    const int nid  = (xcd < r ? xcd*(q+1) : r*(q+1) + (xcd - r)*q) + pos;
    const int m0   = (nid % GM) * 256;
    const int n0   = (nid / GM) * 256;

    const int tid  = threadIdx.x;
    const int lane = tid & 63;
    const int wave = tid >> 6;
    const int wm   = wave >> 2;      // 0..1  (M half)
    const int wn   = wave & 3;       // 0..3  (N quarter)
    const int fr   = lane & 15;
    const int fg   = lane >> 4;

    // staging geometry: thread covers (row grow + j*64, slot tid&7);
    // fetches k-group gks = slot ^ (row&7)  (j*64 preserves row&7)
    const int grow = tid >> 3;                  // 0..63
    const int gks  = (tid & 7) ^ (grow & 7);
    const int lofs = tid * 8;                   // bf16 units per batch

    const bf16_t* pA = E + (size_t)(m0 + grow)*TGT + gks*8;
    const bf16_t* pB = M + (size_t)(n0 + grow)*TGT + gks*8;

    // fragment-read swizzled slots (row&7 == fr&7 since row bases are x16)
    const int xs0  = (fg)     ^ (fr & 7);       // kk = 0
    const int xs1  = (4 + fg) ^ (fr & 7);       // kk = 1
    const int arow = (wm*128 + fr) * 64;        // bf16 units
    const int brow = (wn*64  + fr) * 64;

    floatx4 acc[8][4];
#pragma unroll
    for (int i = 0; i < 8; ++i)
#pragma unroll
        for (int j = 0; j < 4; ++j) acc[i][j] = (floatx4)0.0f;

#define STG_A(buf, tk, j) load_lds16(pA + (size_t)(j)*64*TGT + (tk)*64, \
                                     &SA[buf][(j)*4096 + lofs])
#define STG_B(buf, tk, j) load_lds16(pB + (size_t)(j)*64*TGT + (tk)*64, \
                                     &SB[buf][(j)*4096 + lofs])

#define RD_A(buf, mh, A_) do { \
    _Pragma("unroll") \
    for (int _m = 0; _m < 4; ++_m) { \
        A_[_m][0] = *(const bf16x8*)&SA[buf][arow + ((mh)*4+_m)*1024 + xs0*8]; \
        A_[_m][1] = *(const bf16x8*)&SA[buf][arow + ((mh)*4+_m)*1024 + xs1*8]; } } while (0)

#define RD_B(buf, nh, B_) do { \
    _Pragma("unroll") \
    for (int _n = 0; _n < 2; ++_n) { \
        B_[_n][0] = *(const bf16x8*)&SB[buf][brow + ((nh)*2+_n)*1024 + xs0*8]; \
        B_[_n][1] = *(const bf16x8*)&SB[buf][brow + ((nh)*2+_n)*1024 + xs1*8]; } } while (0)

#define MFMA16(mh, nh, A_, B_) do { \
    __builtin_amdgcn_s_setprio(1); \
    _Pragma("unroll") \
    for (int _m = 0; _m < 4; ++_m) \
    _Pragma("unroll") \
    for (int _n = 0; _n < 2; ++_n) { \
        acc[(mh)*4+_m][(nh)*2+_n] = __builtin_amdgcn_mfma_f32_16x16x32_bf16( \
            A_[_m][0], B_[_n][0], acc[(mh)*4+_m][(nh)*2+_n], 0, 0, 0); \
        acc[(mh)*4+_m][(nh)*2+_n] = __builtin_amdgcn_mfma_f32_16x16x32_bf16( \
            A_[_m][1], B_[_n][1], acc[(mh)*4+_m][(nh)*2+_n], 0, 0, 0); } \
    __builtin_amdgcn_s_setprio(0); } while (0)

#define TILE(bufc, bufn, tkA, tkB) do { \
    RD_A(bufc, 0, aa); RD_B(bufc, 0, bb); \
    STG_A(bufn, tkA, 0); STG_A(bufn, tkA, 1); \
    BAR(); LGKM0(); MFMA16(0, 0, aa, bb); BAR(); \
    RD_B(bufc, 1, bc); \
    STG_A(bufn, tkA, 2); STG_A(bufn, tkA, 3); \
    BAR(); LGKM0(); MFMA16(0, 1, aa, bc); BAR(); \
    RD_A(bufc, 1, aa); \
    STG_B(bufc, tkB, 0); STG_B(bufc, tkB, 1); \
    BAR(); LGKM0(); MFMA16(1, 0, aa, bb); BAR(); \
    STG_B(bufc, tkB, 2); STG_B(bufc, tkB, 3); \
    VM4(); BAR(); MFMA16(1, 1, aa, bc); BAR(); \
} while (0)

    bf16x8 aa[4][2], bb[2][2], bc[2][2];

    // prologue: A(0),B(0) -> buf0 (8 loads), B(1) -> buf1 (4 loads);
    // vmcnt(4) -> tile 0 fully landed, B(1) in flight = steady-state entry.
#pragma unroll
    for (int j = 0; j < 4; ++j) STG_A(0, 0, j);
#pragma unroll
    for (int j = 0; j < 4; ++j) STG_B(0, 0, j);
#pragma unroll
    for (int j = 0; j < 4; ++j) STG_B(1, 1, j);
    VM4(); BAR();

    for (int t = 0; t < 16; t += 2) {
        const int a0 = t + 1;                       // <= 15 always (t even <=14)
        const int b0 = (t + 2 < 16) ? t + 2 : 15;   // clamp: dummy re-stage
        TILE(0, 1, a0, b0);
        const int a1 = (t + 2 < 16) ? t + 2 : 15;
        const int b1 = (t + 3 < 16) ? t + 3 : 15;
        TILE(1, 0, a1, b1);
    }

#undef STG_A
#undef STG_B
#undef RD_A
#undef RD_B
#undef MFMA16
#undef TILE

    // epilogue: d2 + min over this block's 256 columns, atomicMin per row
    float mn[4];
#pragma unroll
    for (int tn = 0; tn < 4; ++tn)
        mn[tn] = mnorm[n0 + wn*64 + tn*16 + fr];
    const int rowq = fg * 4;
#pragma unroll
    for (int tm = 0; tm < 8; ++tm) {
#pragma unroll
        for (int r = 0; r < 4; ++r) {
            const int row = m0 + wm*128 + tm*16 + rowq + r;
            const float en = enorm[row];
            float best = 1e38f;
#pragma unroll
            for (int tn = 0; tn < 4; ++tn)
                best = fminf(best, en + mn[tn] - 2.0f*acc[tm][tn][r]);
#pragma unroll
            for (int off = 1; off < 16; off <<= 1)
                best = fminf(best, __shfl_xor(best, off, 64));
            if (fr == 0)
                atomicMin(&out_min[row], __float_as_int(best));
        }
    }
}

// ---------------------------------------------------------------------------
// Kernel F (fused): bilinear 24x24 -> 384x384 upsample; blocks 0..7 also
// compute the per-batch image score (max over 576 patches).
// ---------------------------------------------------------------------------
__global__ __launch_bounds__(256) void finish_kernel(
    const int* __restrict__ ps_bits, float* __restrict__ scores,
    float* __restrict__ masks)
{
    __shared__ float red[4];
    const int tid = threadIdx.x;
    const int idx = blockIdx.x*256 + tid;
    const int b   = idx / (IMG_*IMG_);
    const int p   = idx - b*(IMG_*IMG_);
    const int oy  = p / IMG_, ox = p - oy*IMG_;

    float fy = (oy + 0.5f) * (1.0f/16.0f) - 0.5f;
    float fx = (ox + 0.5f) * (1.0f/16.0f) - 0.5f;
    int y0 = (int)floorf(fy); float ty = fy - (float)y0;
    int x0 = (int)floorf(fx); float tx = fx - (float)x0;
    int y0c = min(max(y0, 0), GRID_-1), y1c = min(max(y0+1, 0), GRID_-1);
    int x0c = min(max(x0, 0), GRID_-1), x1c = min(max(x0+1, 0), GRID_-1);

    const int* psb = ps_bits + b*GRID_*GRID_;
    float v00 = __int_as_float(psb[y0c*GRID_ + x0c]);
    float v01 = __int_as_float(psb[y0c*GRID_ + x1c]);
    float v10 = __int_as_float(psb[y1c*GRID_ + x0c]);
    float v11 = __int_as_float(psb[y1c*GRID_ + x1c]);
    float v0 = v00 + (v01 - v00)*tx;
    float v1 = v10 + (v11 - v10)*tx;
    masks[idx] = v0 + (v1 - v0)*ty;

    if (blockIdx.x < B_) {
        const int sb = blockIdx.x;
        float m = -1e38f;
        for (int i = tid; i < GRID_*GRID_; i += 256)
            m = fmaxf(m, __int_as_float(ps_bits[sb*GRID_*GRID_ + i]));
        for (int off = 32; off > 0; off >>= 1) m = fmaxf(m, __shfl_down(m, off, 64));
        if ((tid & 63) == 0) red[tid >> 6] = m;
        __syncthreads();
        if (tid == 0)
            scores[sb] = fmaxf(fmaxf(red[0], red[1]), fmaxf(red[2], red[3]));
    }
}

// ---------------------------------------------------------------------------
extern "C" void kernel_launch(void* const* d_in, const int* in_sizes, int n_in,
                              void* d_out, int out_size, void* d_ws, size_t ws_size,
                              hipStream_t stream)
{
    const float* f6  = (const float*)d_in[0];
    const float* f8  = (const float*)d_in[1];
    const float* f10 = (const float*)d_in[2];
    const float* mb  = (const float*)d_in[3];
    float* out = (float*)d_out;

    char* ws = (char*)d_ws;
    bf16_t* emb  = (bf16_t*)ws;  ws += (size_t)NPATCH*TGT*sizeof(bf16_t);
    bf16_t* mbf  = (bf16_t*)ws;  ws += (size_t)NMEM_PAD*TGT*sizeof(bf16_t);
    float* enorm = (float*)ws;   ws += (size_t)NPATCH*sizeof(float);
    float* mnorm = (float*)ws;   ws += (size_t)NMEM_PAD*sizeof(float);
    int* psbits  = (int*)ws;     ws += (size_t)NPATCH*sizeof(int);

    hipLaunchKernelGGL(prep_kernel, dim3(NPATCH + NMEM_PAD/4), dim3(256), 0, stream,
                       f6, f8, f10, mb, emb, enorm, mbf, mnorm, psbits);
    hipLaunchKernelGGL(nnmin_kernel, dim3(GM, GN), dim3(512),
                       0, stream, emb, mbf, enorm, mnorm, psbits);
    hipLaunchKernelGGL(finish_kernel, dim3((B_*IMG_*IMG_)/256), dim3(256), 0, stream,
                       psbits, out, out + B_);
}